// Round 1
// 378.378 us; speedup vs baseline: 1.0701x; 1.0701x over previous
//
#include <hip/hip_runtime.h>
#include <math.h>

// ---------------------------------------------------------------------------
// NTM cell. ALL I/O fp32 (per reference setup_inputs dtypes); bf16 MFMA used
// internally for the LSTM GEMM (test tolerance is bf16-grade).
// B=4096, IN=64, U=256, N=128, W=64, OUT=64, NPH=70, P=268, K_lstm=384.
// Pipeline: k_transpose -> k_lstm (MFMA) -> k_params (+head-param prep)
//           -> k_addr (register-resident M, 3 barriers) -> k_out
// ---------------------------------------------------------------------------

typedef unsigned short u16;
typedef __attribute__((ext_vector_type(8))) __bf16 bf16x8;
typedef __attribute__((ext_vector_type(8))) unsigned short u16x8;
typedef __attribute__((ext_vector_type(4))) float f32x4;

#define DI __device__ __forceinline__

static constexpr int Bn = 4096;

// output element offsets (order: out, read_vec, w_read, w_write, M_new, h_new, c_new)
static constexpr size_t OFF_OUT = 0;
static constexpr size_t OFF_RV  = (size_t)Bn * 64;
static constexpr size_t OFF_WR  = OFF_RV + (size_t)Bn * 64;
static constexpr size_t OFF_WW  = OFF_WR + (size_t)Bn * 128;
static constexpr size_t OFF_M   = OFF_WW + (size_t)Bn * 128;
static constexpr size_t OFF_H   = OFF_M + (size_t)Bn * 128 * 64;
static constexpr size_t OFF_C   = OFF_H + (size_t)Bn * 256;

// ws byte offsets
static constexpr size_t WS_WT = 0;                             // bf16 1024x384
static constexpr size_t WS_H  = 786432;                        // f32 4096x256
static constexpr size_t WS_P  = WS_H + (size_t)Bn * 256 * 4;   // f32 4096x268 (prepped head params)
static constexpr size_t WS_RV = WS_P + (size_t)Bn * 268 * 4;   // f32 4096x64

DI u16 f2b(float f) {
  unsigned int u = __float_as_uint(f);
  unsigned int r = (u + 0x7fffu + ((u >> 16) & 1u)) >> 16;  // RNE
  return (u16)r;
}
DI float sigf(float x) { return 1.f / (1.f + expf(-x)); }

DI void gld16(const void* g, void* l) {
  __builtin_amdgcn_global_load_lds(
      (const __attribute__((address_space(1))) unsigned int*)g,
      (__attribute__((address_space(3))) unsigned int*)l, 16, 0, 0);
}

DI float wsum(float v) {
  v += __shfl_xor(v, 32, 64); v += __shfl_xor(v, 16, 64);
  v += __shfl_xor(v, 8, 64);  v += __shfl_xor(v, 4, 64);
  v += __shfl_xor(v, 2, 64);  v += __shfl_xor(v, 1, 64);
  return v;
}
DI float wmax(float v) {
  v = fmaxf(v, __shfl_xor(v, 32, 64)); v = fmaxf(v, __shfl_xor(v, 16, 64));
  v = fmaxf(v, __shfl_xor(v, 8, 64));  v = fmaxf(v, __shfl_xor(v, 4, 64));
  v = fmaxf(v, __shfl_xor(v, 2, 64));  v = fmaxf(v, __shfl_xor(v, 1, 64));
  return v;
}
DI float rsum16(float v) {  // reduce across 16-lane groups
  v += __shfl_xor(v, 1, 64); v += __shfl_xor(v, 2, 64);
  v += __shfl_xor(v, 4, 64); v += __shfl_xor(v, 8, 64);
  return v;
}

// ---------------------------------------------------------------------------
// K0: Wt[c][k] = bf16( k<128 ? W_k[k][c] : W_r[k-128][c] )   c<1024, k<384
// ---------------------------------------------------------------------------
__global__ __launch_bounds__(256) void k_transpose(
    const float* __restrict__ W_k, const float* __restrict__ W_r, u16* __restrict__ Wt)
{
  __shared__ float tile[64][65];
  const int c0 = blockIdx.x * 64, k0 = blockIdx.y * 64;
  const int t = threadIdx.x;
  {
    const int r2 = t >> 4, cc = (t & 15) * 4;
#pragma unroll
    for (int rr = 0; rr < 4; rr++) {
      int row = rr * 16 + r2;  // k-row within block
      const float* src = (k0 < 128) ? (W_k + (size_t)(k0 + row) * 1024)
                                    : (W_r + (size_t)(k0 - 128 + row) * 1024);
      float4 v = *(const float4*)(src + c0 + cc);
      tile[row][cc + 0] = v.x; tile[row][cc + 1] = v.y;
      tile[row][cc + 2] = v.z; tile[row][cc + 3] = v.w;
    }
  }
  __syncthreads();
  const int wr = t >> 2, wc0 = (t & 3) * 16;
  u16* dst = Wt + (size_t)(c0 + wr) * 384 + k0 + wc0;
#pragma unroll
  for (int j = 0; j < 16; j++) dst[j] = f2b(tile[wc0 + j][wr]);
}

// ---------------------------------------------------------------------------
// K1: fused LSTM. z = [x|rv0|h0] @ [W_k;W_r] + b -> gates -> h_new, c_new.
// Block: 64 batch rows x (4 gates x 32 u-cols). A: fp32 global -> bf16 LDS
// (ds_write_b128, XOR chunk swizzle). B: bf16 Wt via global_load_lds.
// ---------------------------------------------------------------------------
__global__ __launch_bounds__(256) void k_lstm(
    const float* __restrict__ x, const float* __restrict__ rv0, const float* __restrict__ h0,
    const float* __restrict__ c0, const float* __restrict__ b_lstm, const u16* __restrict__ Wt,
    float* __restrict__ h_ws, float* __restrict__ out)
{
  __shared__ __align__(16) u16 As[64 * 32];   // 4 KB
  __shared__ __align__(16) u16 Bs[128 * 32];  // 8 KB
  const int t = threadIdx.x;
  const int wv = t >> 6, lane = t & 63;
  const int m0 = blockIdx.x * 64, u0 = blockIdx.y * 32;
  const int lane15 = lane & 15, quad = lane >> 4;

  f32x4 acc[8];
#pragma unroll
  for (int i = 0; i < 8; i++) acc[i] = (f32x4){0.f, 0.f, 0.f, 0.f};

  const int mrow = wv * 16 + lane15;
  const int aChunk = mrow * 4 + (quad ^ (mrow & 3));

  for (int kstep = 0; kstep < 12; ++kstep) {
    const int k0 = kstep * 32;
    const float* srcA; int ldA, colA;
    if (k0 < 64)       { srcA = x;   ldA = 64;  colA = k0; }
    else if (k0 < 128) { srcA = rv0; ldA = 64;  colA = k0 - 64; }
    else               { srcA = h0;  ldA = 256; colA = k0 - 128; }
    {
      const int m = t >> 2, kq = t & 3;
      const float* ap = srcA + (size_t)(m0 + m) * ldA + colA + kq * 8;
      float4 v0 = *(const float4*)ap;
      float4 v1 = *(const float4*)(ap + 4);
      u16x8 pk;
      pk[0] = f2b(v0.x); pk[1] = f2b(v0.y); pk[2] = f2b(v0.z); pk[3] = f2b(v0.w);
      pk[4] = f2b(v1.x); pk[5] = f2b(v1.y); pk[6] = f2b(v1.z); pk[7] = f2b(v1.w);
      *(u16x8*)(As + (m * 4 + (kq ^ (m & 3))) * 8) = pk;
    }
#pragma unroll
    for (int r = 0; r < 2; ++r) {
      int lin = r * 256 + t;
      int cl = lin >> 2, kq = (lin & 3) ^ (cl & 3);
      int cg = (cl >> 5) * 256 + u0 + (cl & 31);  // gate-stripe gather
      gld16(Wt + (size_t)cg * 384 + k0 + kq * 8, Bs + lin * 8);
    }
    __syncthreads();  // drains lgkm (ds_write) + vm (global_load_lds)
    bf16x8 a = *(const bf16x8*)(As + aChunk * 8);
#pragma unroll
    for (int nt = 0; nt < 8; ++nt) {
      int crow = nt * 16 + lane15;
      bf16x8 bfr = *(const bf16x8*)(Bs + (crow * 4 + (quad ^ (crow & 3))) * 8);
      acc[nt] = __builtin_amdgcn_mfma_f32_16x16x32_bf16(a, bfr, acc[nt], 0, 0, 0);
    }
    __syncthreads();
  }

  // acc[g*2+up]: gate g, col u0+up*16+lane15, rows quad*4+r (within wave's 16-row slab)
#pragma unroll
  for (int up = 0; up < 2; ++up) {
    const int u = u0 + up * 16 + lane15;
    const float bi  = b_lstm[u];
    const float bff = b_lstm[256 + u];
    const float bg  = b_lstm[512 + u];
    const float bo  = b_lstm[768 + u];
#pragma unroll
    for (int r = 0; r < 4; ++r) {
      const int brow = m0 + wv * 16 + quad * 4 + r;
      float zi = acc[0 + up][r] + bi;
      float zf = acc[2 + up][r] + bff;
      float zg = acc[4 + up][r] + bg;
      float zo = acc[6 + up][r] + bo;
      float cold = c0[(size_t)brow * 256 + u];
      float cn = sigf(zf) * cold + sigf(zi) * tanhf(zg);
      float hn = sigf(zo) * tanhf(cn);
      h_ws[(size_t)brow * 256 + u] = hn;
      out[OFF_H + (size_t)brow * 256 + u] = hn;
      out[OFF_C + (size_t)brow * 256 + u] = cn;
    }
  }
}

// ---------------------------------------------------------------------------
// K2: params = clip(h_new @ W_p + b_p, +-20) with PERMUTED column layout, then
// head-param prep fused in the epilogue. Output knb[b][268]:
//   [0,64)   kn0  (normalized tanh key, head 0)        <- orig cols 0..63
//   [64,128) kn1  (head 1)                             <- orig cols 70..133
//   [128,134) scal0 raw clipped (beta,g,s0,s1,s2,gam)  <- orig cols 64..69
//   [134,140) scal1 raw clipped                        <- orig cols 134..139
//   [140,204) erase = sigmoid(p)                       <- orig cols 140..203
//   [204,268) add   = tanh(p)                          <- orig cols 204..267
// h-row is wave-uniform -> read directly from global (scalar loads), no LDS.
// kn norm: head0 cols on wave0, head1 cols on wave1 -> pure-shuffle reduce.
// ---------------------------------------------------------------------------
__global__ __launch_bounds__(320) void k_params(
    const float* __restrict__ h_ws, const float* __restrict__ W_p,
    const float* __restrict__ b_p, float* __restrict__ knb)
{
  const int b0 = blockIdx.x * 16, t = threadIdx.x;
  const bool active = t < 268;
  int pc;  // original param column feeding output slot t
  if (t < 64) pc = t;
  else if (t < 128) pc = t + 6;
  else if (t < 134) pc = t - 64;
  else pc = t;
  if (!active) pc = 267;  // keep wave 4 convergent; writes are guarded

  const float* wp = W_p + pc;
  const float* hp = h_ws + (size_t)b0 * 256;
  float acc[16];
#pragma unroll
  for (int r = 0; r < 16; r++) acc[r] = 0.f;
  for (int k4 = 0; k4 < 64; k4++) {
    const float wp0 = wp[(k4 * 4 + 0) * 268];
    const float wp1 = wp[(k4 * 4 + 1) * 268];
    const float wp2 = wp[(k4 * 4 + 2) * 268];
    const float wp3 = wp[(k4 * 4 + 3) * 268];
#pragma unroll
    for (int r = 0; r < 16; r++) {
      const f32x4 h4 = *(const f32x4*)(hp + r * 256 + k4 * 4);  // uniform -> s_load
      acc[r] += h4[0] * wp0 + h4[1] * wp1 + h4[2] * wp2 + h4[3] * wp3;
    }
  }
  const float bp = b_p[pc];
  float v[16];
#pragma unroll
  for (int r = 0; r < 16; r++) v[r] = fminf(fmaxf(acc[r] + bp, -20.f), 20.f);

  float* dst = knb + (size_t)b0 * 268 + t;
  if (t < 128) {  // waves 0,1 fully active: per-head key normalize via shuffles
#pragma unroll
    for (int r = 0; r < 16; r++) {
      float kv = tanhf(v[r]);
      float ss = wsum(kv * kv);
      dst[r * 268] = kv * rsqrtf(fmaxf(ss, 1e-12f));
    }
  } else if (t < 140) {
#pragma unroll
    for (int r = 0; r < 16; r++) dst[r * 268] = v[r];           // raw scal
  } else if (t < 204) {
#pragma unroll
    for (int r = 0; r < 16; r++) dst[r * 268] = sigf(v[r]);     // erase
  } else if (t < 268) {
#pragma unroll
    for (int r = 0; r < 16; r++) dst[r * 268] = tanhf(v[r]);    // add
  }
}

// ---------------------------------------------------------------------------
// K3: addressing + read_vec + M_new. One block (256 thr) per batch row.
// Thread (r = t>>4, ch = t&15) owns cols [4ch,4ch+4) of rows {16i + r}; the 8
// row-chunks of M live in REGISTERS across all phases (single HBM read of M,
// no 32 KB LDS stage). Similarity reduces over 16 lanes via shfl; the whole
// softmax/interp/shift/sharpen chain runs in ONE WAVE per head (shuffle roll
// with lane-0/63 fixups) -> only 3 __syncthreads total, ~6.5 KB LDS.
// ---------------------------------------------------------------------------
__global__ __launch_bounds__(256) void k_addr(
    const float* __restrict__ M, const float* __restrict__ w0p,
    const float* __restrict__ w1p, const float* __restrict__ knb,
    float* __restrict__ rv_ws, float* __restrict__ out)
{
  __shared__ float ksim[2][128];
  __shared__ float wfin[2][128];
  __shared__ float rvpart[16][68];  // +4 pad: conflict-free b128 writes

  const int b = blockIdx.x, t = threadIdx.x;
  const int lane = t & 63;
  const int r = t >> 4, ch = t & 15;
  const float* Mb = M + (size_t)b * 8192;
  const float* kb = knb + (size_t)b * 268;

  const f32x4 kn0 = *(const f32x4*)(kb + ch * 4);
  const f32x4 kn1 = *(const f32x4*)(kb + 64 + ch * 4);
  const f32x4 er4 = *(const f32x4*)(kb + 140 + ch * 4);
  const f32x4 ad4 = *(const f32x4*)(kb + 204 + ch * 4);

  f32x4 mv[8];
#pragma unroll
  for (int i = 0; i < 8; i++)
    mv[i] = *(const f32x4*)(Mb + (size_t)(i * 16 + r) * 64 + ch * 4);

  // Phase 2: row norms + cosine similarity (negated, faithful to reference)
#pragma unroll
  for (int i = 0; i < 8; i++) {
    const f32x4 m4 = mv[i];
    float ssm = m4[0] * m4[0] + m4[1] * m4[1] + m4[2] * m4[2] + m4[3] * m4[3];
    float dr  = kn0[0] * m4[0] + kn0[1] * m4[1] + kn0[2] * m4[2] + kn0[3] * m4[3];
    float dw  = kn1[0] * m4[0] + kn1[1] * m4[1] + kn1[2] * m4[2] + kn1[3] * m4[3];
    ssm = rsum16(ssm); dr = rsum16(dr); dw = rsum16(dw);
    if (ch == 0) {
      const float inv = rsqrtf(fmaxf(ssm, 1e-12f));
      ksim[0][i * 16 + r] = -dr * inv;
      ksim[1][i * 16 + r] = -dw * inv;
    }
  }
  __syncthreads();

  // Phase 3: one wave per head, barrier-free internally. Lane l owns n=l, n=l+64.
  if (t < 128) {
    const int h = t >> 6, l = lane;
    const float* sc = kb + 128 + h * 6;
    const float beta = log1pf(expf(sc[0]));
    const float g = sigf(sc[1]);
    const float s0r = sc[2], s1r = sc[3], s2r = sc[4];
    const float mx3 = fmaxf(s0r, fmaxf(s1r, s2r));
    const float e0 = expf(s0r - mx3), e1 = expf(s1r - mx3), e2 = expf(s2r - mx3);
    const float i3 = 1.f / (e0 + e1 + e2);
    const float s0 = e0 * i3, s1 = e1 * i3, s2 = e2 * i3;
    const float gamma = log1pf(expf(sc[5])) + 1.f;

    const float v0 = beta * ksim[h][l];
    const float v1 = beta * ksim[h][l + 64];
    const float mxv = wmax(fmaxf(v0, v1));
    const float ex0 = expf(v0 - mxv), ex1 = expf(v1 - mxv);
    const float sinv = 1.f / wsum(ex0 + ex1);
    const float* wpv = (h ? w1p : w0p) + (size_t)b * 128;
    const float wg0 = g * (ex0 * sinv) + (1.f - g) * wpv[l];
    const float wg1 = g * (ex1 * sinv) + (1.f - g) * wpv[l + 64];
    // circular shift +-1 across the 128-ring split as (v0: n=l, v1: n=l+64)
    const float a   = __shfl(wg0, (l + 63) & 63, 64);
    const float bsh = __shfl(wg1, (l + 63) & 63, 64);
    const float c   = __shfl(wg0, (l + 1) & 63, 64);
    const float d   = __shfl(wg1, (l + 1) & 63, 64);
    const float p0 = (l == 0) ? bsh : a;   // wg[n-1] for n=l
    const float p1 = (l == 0) ? a : bsh;   // wg[n-1] for n=l+64
    const float n0 = (l == 63) ? d : c;    // wg[n+1] for n=l
    const float n1 = (l == 63) ? c : d;    // wg[n+1] for n=l+64
    const float w_0 = s0 * wg0 + s1 * p0 + s2 * n0;
    const float w_1 = s0 * wg1 + s1 * p1 + s2 * n1;
    const float ws0 = powf(w_0, gamma), ws1 = powf(w_1, gamma);
    const float it = 1.f / wsum(ws0 + ws1);
    const float wf0 = ws0 * it, wf1 = ws1 * it;
    wfin[h][l] = wf0; wfin[h][l + 64] = wf1;
    const size_t ob = (h ? OFF_WW : OFF_WR) + (size_t)b * 128;
    out[ob + l] = wf0; out[ob + l + 64] = wf1;
  }
  __syncthreads();

  // Phase 4: M_new + read_vec from the register copy of M
  f32x4 rvp = (f32x4){0.f, 0.f, 0.f, 0.f};
  float* mout = out + OFF_M + (size_t)b * 8192;
#pragma unroll
  for (int i = 0; i < 8; i++) {
    const int n = i * 16 + r;
    const float wr = wfin[0][n], ww = wfin[1][n];  // LDS broadcast
    const f32x4 m4 = mv[i];
    f32x4 nw;
#pragma unroll
    for (int j = 0; j < 4; j++) nw[j] = m4[j] * (1.f - ww * er4[j]) + ww * ad4[j];
    *(f32x4*)(mout + (size_t)n * 64 + ch * 4) = nw;
#pragma unroll
    for (int j = 0; j < 4; j++) rvp[j] += wr * m4[j];
  }
  *(f32x4*)&rvpart[r][ch * 4] = rvp;
  __syncthreads();
  if (t < 64) {
    float rv = 0.f;
#pragma unroll
    for (int r2 = 0; r2 < 16; r2++) rv += rvpart[r2][t];
    out[OFF_RV + (size_t)b * 64 + t] = rv;
    rv_ws[(size_t)b * 64 + t] = rv;
  }
}

// ---------------------------------------------------------------------------
// K4: out = clip([h_new, read_vec] @ W_o + b_o, +-20). 16 rows/block (256
// blocks = 1/CU), wave w owns 4 rows; input rows are wave-uniform -> scalar
// loads from global, no LDS. W_o (80 KB) stays L2-hot.
// ---------------------------------------------------------------------------
__global__ __launch_bounds__(256) void k_out(
    const float* __restrict__ h_ws, const float* __restrict__ rv_ws,
    const float* __restrict__ W_o, const float* __restrict__ b_o,
    float* __restrict__ out)
{
  const int t = threadIdx.x;
  const int c = t & 63, w = t >> 6;
  const int row0 = blockIdx.x * 16 + w * 4;
  const float* h0p = h_ws + (size_t)row0 * 256;
  const float* r0p = rv_ws + (size_t)row0 * 64;
  float acc[4] = {0.f, 0.f, 0.f, 0.f};
  for (int k4 = 0; k4 < 64; k4++) {
    const float wo0 = W_o[(k4 * 4 + 0) * 64 + c];
    const float wo1 = W_o[(k4 * 4 + 1) * 64 + c];
    const float wo2 = W_o[(k4 * 4 + 2) * 64 + c];
    const float wo3 = W_o[(k4 * 4 + 3) * 64 + c];
#pragma unroll
    for (int r = 0; r < 4; r++) {
      const f32x4 h4 = *(const f32x4*)(h0p + r * 256 + k4 * 4);  // uniform
      acc[r] += h4[0] * wo0 + h4[1] * wo1 + h4[2] * wo2 + h4[3] * wo3;
    }
  }
  for (int k4 = 0; k4 < 16; k4++) {
    const float wo0 = W_o[(256 + k4 * 4 + 0) * 64 + c];
    const float wo1 = W_o[(256 + k4 * 4 + 1) * 64 + c];
    const float wo2 = W_o[(256 + k4 * 4 + 2) * 64 + c];
    const float wo3 = W_o[(256 + k4 * 4 + 3) * 64 + c];
#pragma unroll
    for (int r = 0; r < 4; r++) {
      const f32x4 r4 = *(const f32x4*)(r0p + r * 64 + k4 * 4);   // uniform
      acc[r] += r4[0] * wo0 + r4[1] * wo1 + r4[2] * wo2 + r4[3] * wo3;
    }
  }
  const float bo = b_o[c];
#pragma unroll
  for (int r = 0; r < 4; r++) {
    const float vv = fminf(fmaxf(acc[r] + bo, -20.f), 20.f);
    out[OFF_OUT + (size_t)(row0 + r) * 64 + c] = vv;
  }
}

// ---------------------------------------------------------------------------
extern "C" void kernel_launch(void* const* d_in, const int* in_sizes, int n_in,
                              void* d_out, int out_size, void* d_ws, size_t ws_size,
                              hipStream_t stream)
{
  const float* x   = (const float*)d_in[0];
  const float* h0  = (const float*)d_in[1];
  const float* c0  = (const float*)d_in[2];
  const float* rv0 = (const float*)d_in[3];
  const float* w0p = (const float*)d_in[4];
  const float* w1p = (const float*)d_in[5];
  const float* M   = (const float*)d_in[6];
  const float* W_k = (const float*)d_in[7];
  const float* W_r = (const float*)d_in[8];
  const float* b_l = (const float*)d_in[9];
  const float* W_p = (const float*)d_in[10];
  const float* b_p = (const float*)d_in[11];
  const float* W_o = (const float*)d_in[12];
  const float* b_o = (const float*)d_in[13];
  float* out = (float*)d_out;
  char* ws = (char*)d_ws;
  u16*   Wt    = (u16*)(ws + WS_WT);
  float* h_ws  = (float*)(ws + WS_H);
  float* knb   = (float*)(ws + WS_P);
  float* rv_ws = (float*)(ws + WS_RV);

  k_transpose<<<dim3(16, 6), 256, 0, stream>>>(W_k, W_r, Wt);
  k_lstm<<<dim3(64, 8), 256, 0, stream>>>(x, rv0, h0, c0, b_l, Wt, h_ws, out);
  k_params<<<256, 320, 0, stream>>>(h_ws, W_p, b_p, knb);
  k_addr<<<4096, 256, 0, stream>>>(M, w0p, w1p, knb, rv_ws, out);
  k_out<<<256, 256, 0, stream>>>(h_ws, rv_ws, W_o, b_o, out);
}

// Round 2
// 377.686 us; speedup vs baseline: 1.0721x; 1.0018x over previous
//
#include <hip/hip_runtime.h>
#include <math.h>

// ---------------------------------------------------------------------------
// NTM cell. ALL I/O fp32 (per reference setup_inputs dtypes); bf16 MFMA used
// internally for the LSTM GEMM (test tolerance is bf16-grade).
// B=4096, IN=64, U=256, N=128, W=64, OUT=64, NPH=70, P=268, K_lstm=384.
// Pipeline: k_transpose -> k_lstm (barrier-free MFMA K-loop, wave-private B)
//           -> k_params (+head-param prep) -> k_addr (reg-resident M, DPP
//           reductions) -> k_out
// ---------------------------------------------------------------------------

typedef unsigned short u16;
typedef __attribute__((ext_vector_type(8))) __bf16 bf16x8;
typedef __attribute__((ext_vector_type(8))) unsigned short u16x8;
typedef __attribute__((ext_vector_type(4))) float f32x4;

#define DI __device__ __forceinline__

static constexpr int Bn = 4096;

// output element offsets (order: out, read_vec, w_read, w_write, M_new, h_new, c_new)
static constexpr size_t OFF_OUT = 0;
static constexpr size_t OFF_RV  = (size_t)Bn * 64;
static constexpr size_t OFF_WR  = OFF_RV + (size_t)Bn * 64;
static constexpr size_t OFF_WW  = OFF_WR + (size_t)Bn * 128;
static constexpr size_t OFF_M   = OFF_WW + (size_t)Bn * 128;
static constexpr size_t OFF_H   = OFF_M + (size_t)Bn * 128 * 64;
static constexpr size_t OFF_C   = OFF_H + (size_t)Bn * 256;

// ws byte offsets
static constexpr size_t WS_WT = 0;                             // bf16 1024x384
static constexpr size_t WS_H  = 786432;                        // f32 4096x256
static constexpr size_t WS_P  = WS_H + (size_t)Bn * 256 * 4;   // f32 4096x268 (prepped head params)
static constexpr size_t WS_RV = WS_P + (size_t)Bn * 268 * 4;   // f32 4096x64

DI u16 f2b(float f) {
  unsigned int u = __float_as_uint(f);
  unsigned int r = (u + 0x7fffu + ((u >> 16) & 1u)) >> 16;  // RNE
  return (u16)r;
}
DI float sigf(float x) { return 1.f / (1.f + expf(-x)); }

DI void gld16(const void* g, void* l) {
  __builtin_amdgcn_global_load_lds(
      (const __attribute__((address_space(1))) unsigned int*)g,
      (__attribute__((address_space(3))) unsigned int*)l, 16, 0, 0);
}

DI float wsum(float v) {
  v += __shfl_xor(v, 32, 64); v += __shfl_xor(v, 16, 64);
  v += __shfl_xor(v, 8, 64);  v += __shfl_xor(v, 4, 64);
  v += __shfl_xor(v, 2, 64);  v += __shfl_xor(v, 1, 64);
  return v;
}
DI float wmax(float v) {
  v = fmaxf(v, __shfl_xor(v, 32, 64)); v = fmaxf(v, __shfl_xor(v, 16, 64));
  v = fmaxf(v, __shfl_xor(v, 8, 64));  v = fmaxf(v, __shfl_xor(v, 4, 64));
  v = fmaxf(v, __shfl_xor(v, 2, 64));  v = fmaxf(v, __shfl_xor(v, 1, 64));
  return v;
}

// DPP rotate-reduce: sum over each aligned 16-lane group, VALU-pipe only
// (no ds_bpermute). row_ror:1/2/4/8 = DPP ctrl 0x121/0x122/0x124/0x128.
#define DPP_ROR_ADD(v, ctrl) \
  v += __int_as_float(__builtin_amdgcn_mov_dpp(__float_as_int(v), ctrl, 0xf, 0xf, true))
#define DPP_ROR_MAX(v, ctrl) \
  v = fmaxf(v, __int_as_float(__builtin_amdgcn_mov_dpp(__float_as_int(v), ctrl, 0xf, 0xf, true)))

DI float rsum16d(float v) {
  DPP_ROR_ADD(v, 0x121); DPP_ROR_ADD(v, 0x122);
  DPP_ROR_ADD(v, 0x124); DPP_ROR_ADD(v, 0x128);
  return v;  // all 16 lanes of each group hold the group sum
}
DI float red64s(float v) {  // full-wave sum: 4 DPP + 2 shfl
  v = rsum16d(v);
  v += __shfl_xor(v, 16, 64); v += __shfl_xor(v, 32, 64);
  return v;
}
DI float red64m(float v) {  // full-wave max: 4 DPP + 2 shfl
  DPP_ROR_MAX(v, 0x121); DPP_ROR_MAX(v, 0x122);
  DPP_ROR_MAX(v, 0x124); DPP_ROR_MAX(v, 0x128);
  v = fmaxf(v, __shfl_xor(v, 16, 64)); v = fmaxf(v, __shfl_xor(v, 32, 64));
  return v;
}

// ---------------------------------------------------------------------------
// K0: Wt[c][k] = bf16( k<128 ? W_k[k][c] : W_r[k-128][c] )   c<1024, k<384
// ---------------------------------------------------------------------------
__global__ __launch_bounds__(256) void k_transpose(
    const float* __restrict__ W_k, const float* __restrict__ W_r, u16* __restrict__ Wt)
{
  __shared__ float tile[64][65];
  const int c0 = blockIdx.x * 64, k0 = blockIdx.y * 64;
  const int t = threadIdx.x;
  {
    const int r2 = t >> 4, cc = (t & 15) * 4;
#pragma unroll
    for (int rr = 0; rr < 4; rr++) {
      int row = rr * 16 + r2;  // k-row within block
      const float* src = (k0 < 128) ? (W_k + (size_t)(k0 + row) * 1024)
                                    : (W_r + (size_t)(k0 - 128 + row) * 1024);
      float4 v = *(const float4*)(src + c0 + cc);
      tile[row][cc + 0] = v.x; tile[row][cc + 1] = v.y;
      tile[row][cc + 2] = v.z; tile[row][cc + 3] = v.w;
    }
  }
  __syncthreads();
  const int wr = t >> 2, wc0 = (t & 3) * 16;
  u16* dst = Wt + (size_t)(c0 + wr) * 384 + k0 + wc0;
#pragma unroll
  for (int j = 0; j < 16; j++) dst[j] = f2b(tile[wc0 + j][wr]);
}

// ---------------------------------------------------------------------------
// K1: fused LSTM, barrier-free K-loop.
// Block = 64 batch rows x 128 gate-cols (4 gates x 32 u). Wave wv owns GATE wv
// entirely (its 32 u-cols), so its B-tile is wave-private: gld16 into a
// per-wave triple-buffered LDS slot with counted s_waitcnt vmcnt(N) -- NO
// __syncthreads in the 12-step K-loop. A ([x|rv0|h0] rows, bf16) is staged
// ONCE (48 KB, read-only afterwards). Gate recombine goes through a 32 KB
// z-buffer aliased over the dead A arena (XOR-swizzled to break the p*256B
// stride). 3 barriers total (vs 24 before).
// ---------------------------------------------------------------------------
__global__ __launch_bounds__(256) void k_lstm(
    const float* __restrict__ x, const float* __restrict__ rv0, const float* __restrict__ h0,
    const float* __restrict__ c0, const float* __restrict__ b_lstm, const u16* __restrict__ Wt,
    float* __restrict__ h_ws, float* __restrict__ out)
{
  __shared__ __align__(16) char arena[49152];    // As (48 KB bf16) then zbuf (32 KB f32)
  __shared__ __align__(16) u16 BsA[4][3][1024];  // per-wave 3-deep B buffers (24 KB)
  u16* As = (u16*)arena;
  float* zbuf = (float*)arena;

  const int t = threadIdx.x;
  const int wv = t >> 6, lane = t & 63;
  const int l15 = lane & 15, qd = lane >> 4;
  const int m0 = blockIdx.x * 64, u0 = blockIdx.y * 32;

  // ---- stage A rows m0..m0+63 as bf16; LDS chunk = (kqg*64 + row) * 8 u16
#pragma unroll 4
  for (int i = 0; i < 12; ++i) {
    const int kqg = i * 4 + wv;  // 0..47 (8-col chunk index over K=384)
    const int row = lane;
    const float* src; int ldA, cbase;
    if (kqg < 8)       { src = x;   ldA = 64;  cbase = kqg * 8; }
    else if (kqg < 16) { src = rv0; ldA = 64;  cbase = (kqg - 8) * 8; }
    else               { src = h0;  ldA = 256; cbase = (kqg - 16) * 8; }
    const float* ap = src + (size_t)(m0 + row) * ldA + cbase;
    float4 v0 = *(const float4*)ap;
    float4 v1 = *(const float4*)(ap + 4);
    u16x8 pk;
    pk[0] = f2b(v0.x); pk[1] = f2b(v0.y); pk[2] = f2b(v0.z); pk[3] = f2b(v0.w);
    pk[4] = f2b(v1.x); pk[5] = f2b(v1.y); pk[6] = f2b(v1.z); pk[7] = f2b(v1.w);
    *(u16x8*)(As + (size_t)(kqg * 64 + row) * 8) = pk;
  }
  __syncthreads();  // As ready (drains the stage loads too)

  // ---- wave-private B stream: gate = wv, cols u0..u0+31 of that gate.
  // Bs chunk layout per buffer: chunk = q*32 + c (q = k-quad, c = col), 16 B.
  const int bq = lane >> 5;           // sub-quad select for the two gld16 calls
  const int bc = lane & 31;           // col within the 32-col slice
  const u16* wsrc = Wt + (size_t)(wv * 256 + u0 + bc) * 384;

  {  // prologue: prefetch kstep 0 and 1
    u16* d0 = &BsA[wv][0][0];
    gld16(wsrc + 0 * 32 + bq * 8, d0);
    gld16(wsrc + 0 * 32 + (2 + bq) * 8, d0 + 512);
    u16* d1 = &BsA[wv][1][0];
    gld16(wsrc + 1 * 32 + bq * 8, d1);
    gld16(wsrc + 1 * 32 + (2 + bq) * 8, d1 + 512);
  }

  f32x4 acc[8];
#pragma unroll
  for (int i = 0; i < 8; i++) acc[i] = (f32x4){0.f, 0.f, 0.f, 0.f};

#pragma unroll
  for (int ks = 0; ks < 12; ++ks) {
    if (ks < 10) {  // prefetch ks+2 (2 gld16 -> 2 KB)
      u16* d = &BsA[wv][(ks + 2) % 3][0];
      const u16* s = wsrc + (ks + 2) * 32;
      gld16(s + bq * 8, d);
      gld16(s + (2 + bq) * 8, d + 512);
    }
    // counted wait: only gld16s are outstanding in this loop. In-order vmcnt
    // retire => <=4 outstanding means kstep ks's 2 loads have landed.
    if (ks < 10)       asm volatile("s_waitcnt vmcnt(4)" ::: "memory");
    else if (ks == 10) asm volatile("s_waitcnt vmcnt(2)" ::: "memory");
    else               asm volatile("s_waitcnt vmcnt(0)" ::: "memory");

    const u16* bs = &BsA[wv][ks % 3][0];
    bf16x8 bf0 = *(const bf16x8*)(bs + (qd * 32 + l15) * 8);
    bf16x8 bf1 = *(const bf16x8*)(bs + (qd * 32 + 16 + l15) * 8);
#pragma unroll
    for (int rf = 0; rf < 4; ++rf) {
      bf16x8 af = *(const bf16x8*)(As + (size_t)((ks * 4 + qd) * 64 + rf * 16 + l15) * 8);
      acc[rf * 2 + 0] = __builtin_amdgcn_mfma_f32_16x16x32_bf16(af, bf0, acc[rf * 2 + 0], 0, 0, 0);
      acc[rf * 2 + 1] = __builtin_amdgcn_mfma_f32_16x16x32_bf16(af, bf1, acc[rf * 2 + 1], 0, 0, 0);
    }
  }
  __syncthreads();  // all waves done reading As -> safe to alias zbuf over it

  // ---- write z to zbuf[gate=wv][p][row] (transposed, block-XOR swizzled).
  // D frag: col p = f*16+l15, rows rf*16 + qd*4 + j  (guide C/D layout).
  {
    char* plane = (char*)zbuf + wv * 8192;
#pragma unroll
    for (int rf = 0; rf < 4; ++rf)
#pragma unroll
      for (int f = 0; f < 2; ++f) {
        const int p = f * 16 + l15;
        int byteo = p * 256 + (rf * 16 + qd * 4) * 4;
        byteo ^= (p & 7) << 4;  // break the 256B-stride bank alias
        *(f32x4*)(plane + byteo) = acc[rf * 2 + f];
      }
  }
  __syncthreads();

  // ---- gate combine: 8 iters x 256 thr cover 64 rows x 32 u-cols
  {
    const int p = t & 31;
    const int u = u0 + p;
    const int sw = (p & 7) << 4;
    const float bi  = b_lstm[u];
    const float bff = b_lstm[256 + u];
    const float bg  = b_lstm[512 + u];
    const float bo  = b_lstm[768 + u];
    const char* zb = (const char*)zbuf;
#pragma unroll
    for (int i = 0; i < 8; ++i) {
      const int row = i * 8 + (t >> 5);
      const int base = (p * 256 + row * 4) ^ sw;
      float zi = *(const float*)(zb + 0 * 8192 + base) + bi;
      float zf = *(const float*)(zb + 1 * 8192 + base) + bff;
      float zg = *(const float*)(zb + 2 * 8192 + base) + bg;
      float zo = *(const float*)(zb + 3 * 8192 + base) + bo;
      const size_t gidx = (size_t)(m0 + row) * 256 + u;
      const float cold = c0[gidx];
      const float cn = sigf(zf) * cold + sigf(zi) * tanhf(zg);
      const float hn = sigf(zo) * tanhf(cn);
      h_ws[gidx] = hn;
      out[OFF_H + gidx] = hn;
      out[OFF_C + gidx] = cn;
    }
  }
}

// ---------------------------------------------------------------------------
// K2: params = clip(h_new @ W_p + b_p, +-20) with PERMUTED column layout, then
// head-param prep fused in the epilogue. Output knb[b][268]:
//   [0,64)   kn0  (normalized tanh key, head 0)        <- orig cols 0..63
//   [64,128) kn1  (head 1)                             <- orig cols 70..133
//   [128,134) scal0 raw clipped (beta,g,s0,s1,s2,gam)  <- orig cols 64..69
//   [134,140) scal1 raw clipped                        <- orig cols 134..139
//   [140,204) erase = sigmoid(p)                       <- orig cols 140..203
//   [204,268) add   = tanh(p)                          <- orig cols 204..267
// ---------------------------------------------------------------------------
__global__ __launch_bounds__(320) void k_params(
    const float* __restrict__ h_ws, const float* __restrict__ W_p,
    const float* __restrict__ b_p, float* __restrict__ knb)
{
  const int b0 = blockIdx.x * 16, t = threadIdx.x;
  const bool active = t < 268;
  int pc;  // original param column feeding output slot t
  if (t < 64) pc = t;
  else if (t < 128) pc = t + 6;
  else if (t < 134) pc = t - 64;
  else pc = t;
  if (!active) pc = 267;  // keep wave 4 convergent; writes are guarded

  const float* wp = W_p + pc;
  const float* hp = h_ws + (size_t)b0 * 256;
  float acc[16];
#pragma unroll
  for (int r = 0; r < 16; r++) acc[r] = 0.f;
  for (int k4 = 0; k4 < 64; k4++) {
    const float wp0 = wp[(k4 * 4 + 0) * 268];
    const float wp1 = wp[(k4 * 4 + 1) * 268];
    const float wp2 = wp[(k4 * 4 + 2) * 268];
    const float wp3 = wp[(k4 * 4 + 3) * 268];
#pragma unroll
    for (int r = 0; r < 16; r++) {
      const f32x4 h4 = *(const f32x4*)(hp + r * 256 + k4 * 4);  // uniform -> s_load
      acc[r] += h4[0] * wp0 + h4[1] * wp1 + h4[2] * wp2 + h4[3] * wp3;
    }
  }
  const float bp = b_p[pc];
  float v[16];
#pragma unroll
  for (int r = 0; r < 16; r++) v[r] = fminf(fmaxf(acc[r] + bp, -20.f), 20.f);

  float* dst = knb + (size_t)b0 * 268 + t;
  if (t < 128) {  // waves 0,1 fully active: per-head key normalize via shuffles
#pragma unroll
    for (int r = 0; r < 16; r++) {
      float kv = tanhf(v[r]);
      float ss = wsum(kv * kv);
      dst[r * 268] = kv * rsqrtf(fmaxf(ss, 1e-12f));
    }
  } else if (t < 140) {
#pragma unroll
    for (int r = 0; r < 16; r++) dst[r * 268] = v[r];           // raw scal
  } else if (t < 204) {
#pragma unroll
    for (int r = 0; r < 16; r++) dst[r * 268] = sigf(v[r]);     // erase
  } else if (t < 268) {
#pragma unroll
    for (int r = 0; r < 16; r++) dst[r * 268] = tanhf(v[r]);    // add
  }
}

// ---------------------------------------------------------------------------
// K3: addressing + read_vec + M_new. One block (256 thr) per batch row.
// Thread (r = t>>4, ch = t&15) owns cols [4ch,4ch+4) of rows {16i + r}; M
// stays in REGISTERS across all phases. 16-lane reductions use DPP row_ror
// (VALU pipe) instead of ds_bpermute shuffles; wave reductions are 4 DPP +
// 2 shfl. 3 __syncthreads total, ~6.5 KB LDS.
// ---------------------------------------------------------------------------
__global__ __launch_bounds__(256) void k_addr(
    const float* __restrict__ M, const float* __restrict__ w0p,
    const float* __restrict__ w1p, const float* __restrict__ knb,
    float* __restrict__ rv_ws, float* __restrict__ out)
{
  __shared__ float ksim[2][128];
  __shared__ float wfin[2][128];
  __shared__ float rvpart[16][68];  // +4 pad: conflict-free b128 writes

  const int b = blockIdx.x, t = threadIdx.x;
  const int lane = t & 63;
  const int r = t >> 4, ch = t & 15;
  const float* Mb = M + (size_t)b * 8192;
  const float* kb = knb + (size_t)b * 268;

  const f32x4 kn0 = *(const f32x4*)(kb + ch * 4);
  const f32x4 kn1 = *(const f32x4*)(kb + 64 + ch * 4);
  const f32x4 er4 = *(const f32x4*)(kb + 140 + ch * 4);
  const f32x4 ad4 = *(const f32x4*)(kb + 204 + ch * 4);

  f32x4 mv[8];
#pragma unroll
  for (int i = 0; i < 8; i++)
    mv[i] = *(const f32x4*)(Mb + (size_t)(i * 16 + r) * 64 + ch * 4);

  // Phase 2: row norms + cosine similarity (negated, faithful to reference)
#pragma unroll
  for (int i = 0; i < 8; i++) {
    const f32x4 m4 = mv[i];
    float ssm = m4[0] * m4[0] + m4[1] * m4[1] + m4[2] * m4[2] + m4[3] * m4[3];
    float dr  = kn0[0] * m4[0] + kn0[1] * m4[1] + kn0[2] * m4[2] + kn0[3] * m4[3];
    float dw  = kn1[0] * m4[0] + kn1[1] * m4[1] + kn1[2] * m4[2] + kn1[3] * m4[3];
    ssm = rsum16d(ssm); dr = rsum16d(dr); dw = rsum16d(dw);
    if (ch == 0) {
      const float inv = rsqrtf(fmaxf(ssm, 1e-12f));
      ksim[0][i * 16 + r] = -dr * inv;
      ksim[1][i * 16 + r] = -dw * inv;
    }
  }
  __syncthreads();

  // Phase 3: one wave per head, barrier-free internally. Lane l owns n=l, n=l+64.
  if (t < 128) {
    const int h = t >> 6, l = lane;
    const float* sc = kb + 128 + h * 6;
    const float beta = log1pf(expf(sc[0]));
    const float g = sigf(sc[1]);
    const float s0r = sc[2], s1r = sc[3], s2r = sc[4];
    const float mx3 = fmaxf(s0r, fmaxf(s1r, s2r));
    const float e0 = expf(s0r - mx3), e1 = expf(s1r - mx3), e2 = expf(s2r - mx3);
    const float i3 = 1.f / (e0 + e1 + e2);
    const float s0 = e0 * i3, s1 = e1 * i3, s2 = e2 * i3;
    const float gamma = log1pf(expf(sc[5])) + 1.f;

    const float v0 = beta * ksim[h][l];
    const float v1 = beta * ksim[h][l + 64];
    const float mxv = red64m(fmaxf(v0, v1));
    const float ex0 = expf(v0 - mxv), ex1 = expf(v1 - mxv);
    const float sinv = 1.f / red64s(ex0 + ex1);
    const float* wpv = (h ? w1p : w0p) + (size_t)b * 128;
    const float wg0 = g * (ex0 * sinv) + (1.f - g) * wpv[l];
    const float wg1 = g * (ex1 * sinv) + (1.f - g) * wpv[l + 64];
    // circular shift +-1 across the 128-ring split as (v0: n=l, v1: n=l+64)
    const float a   = __shfl(wg0, (l + 63) & 63, 64);
    const float bsh = __shfl(wg1, (l + 63) & 63, 64);
    const float c   = __shfl(wg0, (l + 1) & 63, 64);
    const float d   = __shfl(wg1, (l + 1) & 63, 64);
    const float p0 = (l == 0) ? bsh : a;   // wg[n-1] for n=l
    const float p1 = (l == 0) ? a : bsh;   // wg[n-1] for n=l+64
    const float n0 = (l == 63) ? d : c;    // wg[n+1] for n=l
    const float n1 = (l == 63) ? c : d;    // wg[n+1] for n=l+64
    const float w_0 = s0 * wg0 + s1 * p0 + s2 * n0;
    const float w_1 = s0 * wg1 + s1 * p1 + s2 * n1;
    // w_ > 0 always (softmax + sigmoid mix): pow via exp/log fast path
    const float ws0 = expf(gamma * logf(w_0));
    const float ws1 = expf(gamma * logf(w_1));
    const float it = 1.f / red64s(ws0 + ws1);
    const float wf0 = ws0 * it, wf1 = ws1 * it;
    wfin[h][l] = wf0; wfin[h][l + 64] = wf1;
    const size_t ob = (h ? OFF_WW : OFF_WR) + (size_t)b * 128;
    out[ob + l] = wf0; out[ob + l + 64] = wf1;
  }
  __syncthreads();

  // Phase 4: M_new + read_vec from the register copy of M
  f32x4 rvp = (f32x4){0.f, 0.f, 0.f, 0.f};
  float* mout = out + OFF_M + (size_t)b * 8192;
#pragma unroll
  for (int i = 0; i < 8; i++) {
    const int n = i * 16 + r;
    const float wr = wfin[0][n], ww = wfin[1][n];  // LDS broadcast
    const f32x4 m4 = mv[i];
    f32x4 nw;
#pragma unroll
    for (int j = 0; j < 4; j++) nw[j] = m4[j] * (1.f - ww * er4[j]) + ww * ad4[j];
    *(f32x4*)(mout + (size_t)n * 64 + ch * 4) = nw;
#pragma unroll
    for (int j = 0; j < 4; j++) rvp[j] += wr * m4[j];
  }
  *(f32x4*)&rvpart[r][ch * 4] = rvp;
  __syncthreads();
  if (t < 64) {
    float rv = 0.f;
#pragma unroll
    for (int r2 = 0; r2 < 16; r2++) rv += rvpart[r2][t];
    out[OFF_RV + (size_t)b * 64 + t] = rv;
    rv_ws[(size_t)b * 64 + t] = rv;
  }
}

// ---------------------------------------------------------------------------
// K4: out = clip([h_new, read_vec] @ W_o + b_o, +-20). 16 rows/block (256
// blocks = 1/CU), wave w owns 4 rows; input rows are wave-uniform -> scalar
// loads from global, no LDS. W_o (80 KB) stays L2-hot.
// ---------------------------------------------------------------------------
__global__ __launch_bounds__(256) void k_out(
    const float* __restrict__ h_ws, const float* __restrict__ rv_ws,
    const float* __restrict__ W_o, const float* __restrict__ b_o,
    float* __restrict__ out)
{
  const int t = threadIdx.x;
  const int c = t & 63, w = t >> 6;
  const int row0 = blockIdx.x * 16 + w * 4;
  const float* h0p = h_ws + (size_t)row0 * 256;
  const float* r0p = rv_ws + (size_t)row0 * 64;
  float acc[4] = {0.f, 0.f, 0.f, 0.f};
  for (int k4 = 0; k4 < 64; k4++) {
    const float wo0 = W_o[(k4 * 4 + 0) * 64 + c];
    const float wo1 = W_o[(k4 * 4 + 1) * 64 + c];
    const float wo2 = W_o[(k4 * 4 + 2) * 64 + c];
    const float wo3 = W_o[(k4 * 4 + 3) * 64 + c];
#pragma unroll
    for (int r = 0; r < 4; r++) {
      const f32x4 h4 = *(const f32x4*)(h0p + r * 256 + k4 * 4);  // uniform
      acc[r] += h4[0] * wo0 + h4[1] * wo1 + h4[2] * wo2 + h4[3] * wo3;
    }
  }
  for (int k4 = 0; k4 < 16; k4++) {
    const float wo0 = W_o[(256 + k4 * 4 + 0) * 64 + c];
    const float wo1 = W_o[(256 + k4 * 4 + 1) * 64 + c];
    const float wo2 = W_o[(256 + k4 * 4 + 2) * 64 + c];
    const float wo3 = W_o[(256 + k4 * 4 + 3) * 64 + c];
#pragma unroll
    for (int r = 0; r < 4; r++) {
      const f32x4 r4 = *(const f32x4*)(r0p + r * 64 + k4 * 4);   // uniform
      acc[r] += r4[0] * wo0 + r4[1] * wo1 + r4[2] * wo2 + r4[3] * wo3;
    }
  }
  const float bo = b_o[c];
#pragma unroll
  for (int r = 0; r < 4; r++) {
    const float vv = fminf(fmaxf(acc[r] + bo, -20.f), 20.f);
    out[OFF_OUT + (size_t)(row0 + r) * 64 + c] = vv;
  }
}

// ---------------------------------------------------------------------------
extern "C" void kernel_launch(void* const* d_in, const int* in_sizes, int n_in,
                              void* d_out, int out_size, void* d_ws, size_t ws_size,
                              hipStream_t stream)
{
  const float* x   = (const float*)d_in[0];
  const float* h0  = (const float*)d_in[1];
  const float* c0  = (const float*)d_in[2];
  const float* rv0 = (const float*)d_in[3];
  const float* w0p = (const float*)d_in[4];
  const float* w1p = (const float*)d_in[5];
  const float* M   = (const float*)d_in[6];
  const float* W_k = (const float*)d_in[7];
  const float* W_r = (const float*)d_in[8];
  const float* b_l = (const float*)d_in[9];
  const float* W_p = (const float*)d_in[10];
  const float* b_p = (const float*)d_in[11];
  const float* W_o = (const float*)d_in[12];
  const float* b_o = (const float*)d_in[13];
  float* out = (float*)d_out;
  char* ws = (char*)d_ws;
  u16*   Wt    = (u16*)(ws + WS_WT);
  float* h_ws  = (float*)(ws + WS_H);
  float* knb   = (float*)(ws + WS_P);
  float* rv_ws = (float*)(ws + WS_RV);

  k_transpose<<<dim3(16, 6), 256, 0, stream>>>(W_k, W_r, Wt);
  k_lstm<<<dim3(64, 8), 256, 0, stream>>>(x, rv0, h0, c0, b_l, Wt, h_ws, out);
  k_params<<<256, 320, 0, stream>>>(h_ws, W_p, b_p, knb);
  k_addr<<<4096, 256, 0, stream>>>(M, w0p, w1p, knb, rv_ws, out);
  k_out<<<256, 256, 0, stream>>>(h_ws, rv_ws, W_o, b_o, out);
}

// Round 3
// 318.451 us; speedup vs baseline: 1.2715x; 1.1860x over previous
//
#include <hip/hip_runtime.h>
#include <math.h>

// ---------------------------------------------------------------------------
// NTM cell. ALL I/O fp32 (per reference setup_inputs dtypes); bf16 MFMA used
// internally for the LSTM GEMM (test tolerance is bf16-grade).
// B=4096, IN=64, U=256, N=128, W=64, OUT=64, NPH=70, P=268, K_lstm=384.
// Pipeline (4 kernels): k_transpose -> k_lstm (barrier-free MFMA K-loop)
//   -> k_params (params GEMM + head prep + outh = h@W_o[:256])
//   -> k_addr (reg-resident M, nontemporal M streams, fused final out)
// ---------------------------------------------------------------------------

typedef unsigned short u16;
typedef __attribute__((ext_vector_type(8))) __bf16 bf16x8;
typedef __attribute__((ext_vector_type(8))) unsigned short u16x8;
typedef __attribute__((ext_vector_type(4))) float f32x4;

#define DI __device__ __forceinline__

static constexpr int Bn = 4096;

// output element offsets (order: out, read_vec, w_read, w_write, M_new, h_new, c_new)
static constexpr size_t OFF_OUT = 0;
static constexpr size_t OFF_RV  = (size_t)Bn * 64;
static constexpr size_t OFF_WR  = OFF_RV + (size_t)Bn * 64;
static constexpr size_t OFF_WW  = OFF_WR + (size_t)Bn * 128;
static constexpr size_t OFF_M   = OFF_WW + (size_t)Bn * 128;
static constexpr size_t OFF_H   = OFF_M + (size_t)Bn * 128 * 64;
static constexpr size_t OFF_C   = OFF_H + (size_t)Bn * 256;

// ws byte offsets
static constexpr size_t WS_WT = 0;                             // bf16 1024x384
static constexpr size_t WS_H  = 786432;                        // (unused now)
static constexpr size_t WS_P  = WS_H + (size_t)Bn * 256 * 4;   // f32 4096x268 (prepped head params)
static constexpr size_t WS_OH = WS_P + (size_t)Bn * 268 * 4;   // f32 4096x64  (outh = h@W_o[:256])

DI u16 f2b(float f) {
  unsigned int u = __float_as_uint(f);
  unsigned int r = (u + 0x7fffu + ((u >> 16) & 1u)) >> 16;  // RNE
  return (u16)r;
}
DI float sigf(float x) { return 1.f / (1.f + expf(-x)); }

DI void gld16(const void* g, void* l) {
  __builtin_amdgcn_global_load_lds(
      (const __attribute__((address_space(1))) unsigned int*)g,
      (__attribute__((address_space(3))) unsigned int*)l, 16, 0, 0);
}

DI float wsum(float v) {
  v += __shfl_xor(v, 32, 64); v += __shfl_xor(v, 16, 64);
  v += __shfl_xor(v, 8, 64);  v += __shfl_xor(v, 4, 64);
  v += __shfl_xor(v, 2, 64);  v += __shfl_xor(v, 1, 64);
  return v;
}

// DPP rotate-reduce: sum over each aligned 16-lane group, VALU-pipe only
// (no ds_bpermute). row_ror:1/2/4/8 = DPP ctrl 0x121/0x122/0x124/0x128.
#define DPP_ROR_ADD(v, ctrl) \
  v += __int_as_float(__builtin_amdgcn_mov_dpp(__float_as_int(v), ctrl, 0xf, 0xf, true))
#define DPP_ROR_MAX(v, ctrl) \
  v = fmaxf(v, __int_as_float(__builtin_amdgcn_mov_dpp(__float_as_int(v), ctrl, 0xf, 0xf, true)))

DI float rsum16d(float v) {
  DPP_ROR_ADD(v, 0x121); DPP_ROR_ADD(v, 0x122);
  DPP_ROR_ADD(v, 0x124); DPP_ROR_ADD(v, 0x128);
  return v;  // all 16 lanes of each group hold the group sum
}
DI float red64s(float v) {  // full-wave sum: 4 DPP + 2 shfl
  v = rsum16d(v);
  v += __shfl_xor(v, 16, 64); v += __shfl_xor(v, 32, 64);
  return v;
}
DI float red64m(float v) {  // full-wave max: 4 DPP + 2 shfl
  DPP_ROR_MAX(v, 0x121); DPP_ROR_MAX(v, 0x122);
  DPP_ROR_MAX(v, 0x124); DPP_ROR_MAX(v, 0x128);
  v = fmaxf(v, __shfl_xor(v, 16, 64)); v = fmaxf(v, __shfl_xor(v, 32, 64));
  return v;
}

// ---------------------------------------------------------------------------
// K0: Wt[c][k] = bf16( k<128 ? W_k[k][c] : W_r[k-128][c] )   c<1024, k<384
// ---------------------------------------------------------------------------
__global__ __launch_bounds__(256) void k_transpose(
    const float* __restrict__ W_k, const float* __restrict__ W_r, u16* __restrict__ Wt)
{
  __shared__ float tile[64][65];
  const int c0 = blockIdx.x * 64, k0 = blockIdx.y * 64;
  const int t = threadIdx.x;
  {
    const int r2 = t >> 4, cc = (t & 15) * 4;
#pragma unroll
    for (int rr = 0; rr < 4; rr++) {
      int row = rr * 16 + r2;  // k-row within block
      const float* src = (k0 < 128) ? (W_k + (size_t)(k0 + row) * 1024)
                                    : (W_r + (size_t)(k0 - 128 + row) * 1024);
      float4 v = *(const float4*)(src + c0 + cc);
      tile[row][cc + 0] = v.x; tile[row][cc + 1] = v.y;
      tile[row][cc + 2] = v.z; tile[row][cc + 3] = v.w;
    }
  }
  __syncthreads();
  const int wr = t >> 2, wc0 = (t & 3) * 16;
  u16* dst = Wt + (size_t)(c0 + wr) * 384 + k0 + wc0;
#pragma unroll
  for (int j = 0; j < 16; j++) dst[j] = f2b(tile[wc0 + j][wr]);
}

// ---------------------------------------------------------------------------
// K1: fused LSTM, barrier-free K-loop.
// Block = 64 batch rows x 128 gate-cols (4 gates x 32 u). Wave wv owns GATE wv
// entirely (its 32 u-cols), so its B-tile is wave-private: gld16 into a
// per-wave triple-buffered LDS slot with counted s_waitcnt vmcnt(N) -- NO
// __syncthreads in the 12-step K-loop. A ([x|rv0|h0] rows, bf16) is staged
// ONCE (48 KB, read-only afterwards). Gate recombine goes through a 32 KB
// z-buffer aliased over the dead A arena (XOR-swizzled).
// h is written ONLY to out.H (k_params reads it from there).
// ---------------------------------------------------------------------------
__global__ __launch_bounds__(256) void k_lstm(
    const float* __restrict__ x, const float* __restrict__ rv0, const float* __restrict__ h0,
    const float* __restrict__ c0, const float* __restrict__ b_lstm, const u16* __restrict__ Wt,
    float* __restrict__ out)
{
  __shared__ __align__(16) char arena[49152];    // As (48 KB bf16) then zbuf (32 KB f32)
  __shared__ __align__(16) u16 BsA[4][3][1024];  // per-wave 3-deep B buffers (24 KB)
  u16* As = (u16*)arena;
  float* zbuf = (float*)arena;

  const int t = threadIdx.x;
  const int wv = t >> 6, lane = t & 63;
  const int l15 = lane & 15, qd = lane >> 4;
  const int m0 = blockIdx.x * 64, u0 = blockIdx.y * 32;

  // ---- stage A rows m0..m0+63 as bf16; LDS chunk = (kqg*64 + row) * 8 u16
#pragma unroll 4
  for (int i = 0; i < 12; ++i) {
    const int kqg = i * 4 + wv;  // 0..47 (8-col chunk index over K=384)
    const int row = lane;
    const float* src; int ldA, cbase;
    if (kqg < 8)       { src = x;   ldA = 64;  cbase = kqg * 8; }
    else if (kqg < 16) { src = rv0; ldA = 64;  cbase = (kqg - 8) * 8; }
    else               { src = h0;  ldA = 256; cbase = (kqg - 16) * 8; }
    const float* ap = src + (size_t)(m0 + row) * ldA + cbase;
    float4 v0 = *(const float4*)ap;
    float4 v1 = *(const float4*)(ap + 4);
    u16x8 pk;
    pk[0] = f2b(v0.x); pk[1] = f2b(v0.y); pk[2] = f2b(v0.z); pk[3] = f2b(v0.w);
    pk[4] = f2b(v1.x); pk[5] = f2b(v1.y); pk[6] = f2b(v1.z); pk[7] = f2b(v1.w);
    *(u16x8*)(As + (size_t)(kqg * 64 + row) * 8) = pk;
  }
  __syncthreads();  // As ready (drains the stage loads too)

  // ---- wave-private B stream: gate = wv, cols u0..u0+31 of that gate.
  const int bq = lane >> 5;           // sub-quad select for the two gld16 calls
  const int bc = lane & 31;           // col within the 32-col slice
  const u16* wsrc = Wt + (size_t)(wv * 256 + u0 + bc) * 384;

  {  // prologue: prefetch kstep 0 and 1
    u16* d0 = &BsA[wv][0][0];
    gld16(wsrc + 0 * 32 + bq * 8, d0);
    gld16(wsrc + 0 * 32 + (2 + bq) * 8, d0 + 512);
    u16* d1 = &BsA[wv][1][0];
    gld16(wsrc + 1 * 32 + bq * 8, d1);
    gld16(wsrc + 1 * 32 + (2 + bq) * 8, d1 + 512);
  }

  f32x4 acc[8];
#pragma unroll
  for (int i = 0; i < 8; i++) acc[i] = (f32x4){0.f, 0.f, 0.f, 0.f};

#pragma unroll
  for (int ks = 0; ks < 12; ++ks) {
    if (ks < 10) {  // prefetch ks+2 (2 gld16 -> 2 KB)
      u16* d = &BsA[wv][(ks + 2) % 3][0];
      const u16* s = wsrc + (ks + 2) * 32;
      gld16(s + bq * 8, d);
      gld16(s + (2 + bq) * 8, d + 512);
    }
    if (ks < 10)       asm volatile("s_waitcnt vmcnt(4)" ::: "memory");
    else if (ks == 10) asm volatile("s_waitcnt vmcnt(2)" ::: "memory");
    else               asm volatile("s_waitcnt vmcnt(0)" ::: "memory");

    const u16* bs = &BsA[wv][ks % 3][0];
    bf16x8 bf0 = *(const bf16x8*)(bs + (qd * 32 + l15) * 8);
    bf16x8 bf1 = *(const bf16x8*)(bs + (qd * 32 + 16 + l15) * 8);
#pragma unroll
    for (int rf = 0; rf < 4; ++rf) {
      bf16x8 af = *(const bf16x8*)(As + (size_t)((ks * 4 + qd) * 64 + rf * 16 + l15) * 8);
      acc[rf * 2 + 0] = __builtin_amdgcn_mfma_f32_16x16x32_bf16(af, bf0, acc[rf * 2 + 0], 0, 0, 0);
      acc[rf * 2 + 1] = __builtin_amdgcn_mfma_f32_16x16x32_bf16(af, bf1, acc[rf * 2 + 1], 0, 0, 0);
    }
  }
  __syncthreads();  // all waves done reading As -> safe to alias zbuf over it

  // ---- write z to zbuf[gate=wv][p][row] (transposed, block-XOR swizzled).
  {
    char* plane = (char*)zbuf + wv * 8192;
#pragma unroll
    for (int rf = 0; rf < 4; ++rf)
#pragma unroll
      for (int f = 0; f < 2; ++f) {
        const int p = f * 16 + l15;
        int byteo = p * 256 + (rf * 16 + qd * 4) * 4;
        byteo ^= (p & 7) << 4;  // break the 256B-stride bank alias
        *(f32x4*)(plane + byteo) = acc[rf * 2 + f];
      }
  }
  __syncthreads();

  // ---- gate combine: 8 iters x 256 thr cover 64 rows x 32 u-cols
  {
    const int p = t & 31;
    const int u = u0 + p;
    const int sw = (p & 7) << 4;
    const float bi  = b_lstm[u];
    const float bff = b_lstm[256 + u];
    const float bg  = b_lstm[512 + u];
    const float bo  = b_lstm[768 + u];
    const char* zb = (const char*)zbuf;
#pragma unroll
    for (int i = 0; i < 8; ++i) {
      const int row = i * 8 + (t >> 5);
      const int base = (p * 256 + row * 4) ^ sw;
      float zi = *(const float*)(zb + 0 * 8192 + base) + bi;
      float zf = *(const float*)(zb + 1 * 8192 + base) + bff;
      float zg = *(const float*)(zb + 2 * 8192 + base) + bg;
      float zo = *(const float*)(zb + 3 * 8192 + base) + bo;
      const size_t gidx = (size_t)(m0 + row) * 256 + u;
      const float cold = c0[gidx];
      const float cn = sigf(zf) * cold + sigf(zi) * tanhf(zg);
      const float hn = sigf(zo) * tanhf(cn);
      out[OFF_H + gidx] = hn;
      out[OFF_C + gidx] = cn;
    }
  }
}

// ---------------------------------------------------------------------------
// K2: per 8 batch rows: params = clip(h@W_p + b_p, +-20) (permuted cols +
// head prep, as before) PLUS outh = h@W_o[0:256,:] (the h-half of the final
// out GEMM; rv-half and bias/clip are fused into k_addr). h read from out.H
// (wave-uniform -> scalar loads). 512 blocks x 384 thr (2 blocks/CU).
// knb layout: [0,64) kn0 | [64,128) kn1 | [128,134) scal0 | [134,140) scal1 |
//             [140,204) erase | [204,268) add.
// ---------------------------------------------------------------------------
__global__ __launch_bounds__(384) void k_params(
    const float* __restrict__ hsrc, const float* __restrict__ W_p,
    const float* __restrict__ b_p, const float* __restrict__ W_o,
    float* __restrict__ knb, float* __restrict__ oh_ws)
{
  const int b0 = blockIdx.x * 8, t = threadIdx.x;
  if (t >= 332) return;  // no barriers below; waves 0-4 full, wave 5 partial

  int pc;  // original param column feeding output slot t (t<268)
  if (t < 64) pc = t;
  else if (t < 128) pc = t + 6;
  else if (t < 134) pc = t - 64;
  else pc = t;

  const float* wcol; int wstride;
  if (t < 268) { wcol = W_p + pc; wstride = 268; }
  else         { wcol = W_o + (t - 268); wstride = 64; }  // outh column

  const float* hp = hsrc + (size_t)b0 * 256;
  float acc[8];
#pragma unroll
  for (int r = 0; r < 8; r++) acc[r] = 0.f;
  for (int k4 = 0; k4 < 64; k4++) {
    const float w0 = wcol[(k4 * 4 + 0) * wstride];
    const float w1 = wcol[(k4 * 4 + 1) * wstride];
    const float w2 = wcol[(k4 * 4 + 2) * wstride];
    const float w3 = wcol[(k4 * 4 + 3) * wstride];
#pragma unroll
    for (int r = 0; r < 8; r++) {
      const f32x4 h4 = *(const f32x4*)(hp + r * 256 + k4 * 4);  // uniform -> s_load
      acc[r] += h4[0] * w0 + h4[1] * w1 + h4[2] * w2 + h4[3] * w3;
    }
  }

  if (t >= 268) {  // outh: no bias, no clip (applied after rv-half in k_addr)
    float* dst = oh_ws + (size_t)b0 * 64 + (t - 268);
#pragma unroll
    for (int r = 0; r < 8; r++) dst[r * 64] = acc[r];
    return;
  }

  const float bp = b_p[pc];
  float v[8];
#pragma unroll
  for (int r = 0; r < 8; r++) v[r] = fminf(fmaxf(acc[r] + bp, -20.f), 20.f);

  float* dst = knb + (size_t)b0 * 268 + t;
  if (t < 128) {  // waves 0,1 fully active: per-head key normalize via shuffles
#pragma unroll
    for (int r = 0; r < 8; r++) {
      float kv = tanhf(v[r]);
      float ss = wsum(kv * kv);
      dst[r * 268] = kv * rsqrtf(fmaxf(ss, 1e-12f));
    }
  } else if (t < 140) {
#pragma unroll
    for (int r = 0; r < 8; r++) dst[r * 268] = v[r];           // raw scal
  } else if (t < 204) {
#pragma unroll
    for (int r = 0; r < 8; r++) dst[r * 268] = sigf(v[r]);     // erase
  } else {
#pragma unroll
    for (int r = 0; r < 8; r++) dst[r * 268] = tanhf(v[r]);    // add
  }
}

// ---------------------------------------------------------------------------
// K3: addressing + read_vec + M_new + FINAL OUT. One block (256 thr) per
// batch row. Thread (r = t>>4, ch = t&15) owns cols [4ch,4ch+4) of rows
// {16i + r}; M stays in REGISTERS (nontemporal load; M_new nontemporal store
// -- both streams are touch-once, keep them out of L2). Epilogue on wave 0:
// out = clip(outh + rv @ W_o[256:320] + b_o, +-20).
// ---------------------------------------------------------------------------
__global__ __launch_bounds__(256) void k_addr(
    const float* __restrict__ M, const float* __restrict__ w0p,
    const float* __restrict__ w1p, const float* __restrict__ knb,
    const float* __restrict__ oh_ws, const float* __restrict__ W_o,
    const float* __restrict__ b_o, float* __restrict__ out)
{
  __shared__ float ksim[2][128];
  __shared__ float wfin[2][128];
  __shared__ float rvpart[16][68];  // +4 pad: conflict-free b128 writes
  __shared__ float rvs[64];

  const int b = blockIdx.x, t = threadIdx.x;
  const int lane = t & 63;
  const int r = t >> 4, ch = t & 15;
  const float* Mb = M + (size_t)b * 8192;
  const float* kb = knb + (size_t)b * 268;

  const f32x4 kn0 = *(const f32x4*)(kb + ch * 4);
  const f32x4 kn1 = *(const f32x4*)(kb + 64 + ch * 4);
  const f32x4 er4 = *(const f32x4*)(kb + 140 + ch * 4);
  const f32x4 ad4 = *(const f32x4*)(kb + 204 + ch * 4);

  f32x4 mv[8];
#pragma unroll
  for (int i = 0; i < 8; i++)
    mv[i] = __builtin_nontemporal_load(
        (const f32x4*)(Mb + (size_t)(i * 16 + r) * 64 + ch * 4));

  // Phase 2: row norms + cosine similarity (negated, faithful to reference)
#pragma unroll
  for (int i = 0; i < 8; i++) {
    const f32x4 m4 = mv[i];
    float ssm = m4[0] * m4[0] + m4[1] * m4[1] + m4[2] * m4[2] + m4[3] * m4[3];
    float dr  = kn0[0] * m4[0] + kn0[1] * m4[1] + kn0[2] * m4[2] + kn0[3] * m4[3];
    float dw  = kn1[0] * m4[0] + kn1[1] * m4[1] + kn1[2] * m4[2] + kn1[3] * m4[3];
    ssm = rsum16d(ssm); dr = rsum16d(dr); dw = rsum16d(dw);
    if (ch == 0) {
      const float inv = rsqrtf(fmaxf(ssm, 1e-12f));
      ksim[0][i * 16 + r] = -dr * inv;
      ksim[1][i * 16 + r] = -dw * inv;
    }
  }
  __syncthreads();

  // Phase 3: one wave per head, barrier-free internally. Lane l owns n=l, n=l+64.
  if (t < 128) {
    const int h = t >> 6, l = lane;
    const float* sc = kb + 128 + h * 6;
    const float beta = log1pf(expf(sc[0]));
    const float g = sigf(sc[1]);
    const float s0r = sc[2], s1r = sc[3], s2r = sc[4];
    const float mx3 = fmaxf(s0r, fmaxf(s1r, s2r));
    const float e0 = expf(s0r - mx3), e1 = expf(s1r - mx3), e2 = expf(s2r - mx3);
    const float i3 = 1.f / (e0 + e1 + e2);
    const float s0 = e0 * i3, s1 = e1 * i3, s2 = e2 * i3;
    const float gamma = log1pf(expf(sc[5])) + 1.f;

    const float v0 = beta * ksim[h][l];
    const float v1 = beta * ksim[h][l + 64];
    const float mxv = red64m(fmaxf(v0, v1));
    const float ex0 = expf(v0 - mxv), ex1 = expf(v1 - mxv);
    const float sinv = 1.f / red64s(ex0 + ex1);
    const float* wpv = (h ? w1p : w0p) + (size_t)b * 128;
    const float wg0 = g * (ex0 * sinv) + (1.f - g) * wpv[l];
    const float wg1 = g * (ex1 * sinv) + (1.f - g) * wpv[l + 64];
    // circular shift +-1 across the 128-ring split as (v0: n=l, v1: n=l+64)
    const float a   = __shfl(wg0, (l + 63) & 63, 64);
    const float bsh = __shfl(wg1, (l + 63) & 63, 64);
    const float c   = __shfl(wg0, (l + 1) & 63, 64);
    const float d   = __shfl(wg1, (l + 1) & 63, 64);
    const float p0 = (l == 0) ? bsh : a;   // wg[n-1] for n=l
    const float p1 = (l == 0) ? a : bsh;   // wg[n-1] for n=l+64
    const float n0 = (l == 63) ? d : c;    // wg[n+1] for n=l
    const float n1 = (l == 63) ? c : d;    // wg[n+1] for n=l+64
    const float w_0 = s0 * wg0 + s1 * p0 + s2 * n0;
    const float w_1 = s0 * wg1 + s1 * p1 + s2 * n1;
    // w_ > 0 always (softmax + sigmoid mix): pow via exp/log fast path
    const float ws0 = expf(gamma * logf(w_0));
    const float ws1 = expf(gamma * logf(w_1));
    const float it = 1.f / red64s(ws0 + ws1);
    const float wf0 = ws0 * it, wf1 = ws1 * it;
    wfin[h][l] = wf0; wfin[h][l + 64] = wf1;
    const size_t ob = (h ? OFF_WW : OFF_WR) + (size_t)b * 128;
    out[ob + l] = wf0; out[ob + l + 64] = wf1;
  }
  __syncthreads();

  // Phase 4: M_new + read_vec from the register copy of M
  f32x4 rvp = (f32x4){0.f, 0.f, 0.f, 0.f};
  float* mout = out + OFF_M + (size_t)b * 8192;
#pragma unroll
  for (int i = 0; i < 8; i++) {
    const int n = i * 16 + r;
    const float wr = wfin[0][n], ww = wfin[1][n];  // LDS broadcast
    const f32x4 m4 = mv[i];
    f32x4 nw;
#pragma unroll
    for (int j = 0; j < 4; j++) nw[j] = m4[j] * (1.f - ww * er4[j]) + ww * ad4[j];
    __builtin_nontemporal_store(nw, (f32x4*)(mout + (size_t)n * 64 + ch * 4));
#pragma unroll
    for (int j = 0; j < 4; j++) rvp[j] += wr * m4[j];
  }
  *(f32x4*)&rvpart[r][ch * 4] = rvp;
  __syncthreads();

  // Epilogue (wave 0): rv, then out = clip(outh + rv@W_o[256:] + b_o)
  if (t < 64) {
    float rv = 0.f;
#pragma unroll
    for (int r2 = 0; r2 < 16; r2++) rv += rvpart[r2][t];
    out[OFF_RV + (size_t)b * 64 + t] = rv;
    rvs[t] = rv;  // same-wave LDS write->read: hardware-ordered via lgkmcnt

    float o = oh_ws[(size_t)b * 64 + t] + b_o[t];
#pragma unroll 8
    for (int k = 0; k < 64; k++) o += rvs[k] * W_o[(256 + k) * 64 + t];
    out[OFF_OUT + (size_t)b * 64 + t] = fminf(fmaxf(o, -20.f), 20.f);
  }
}

// ---------------------------------------------------------------------------
extern "C" void kernel_launch(void* const* d_in, const int* in_sizes, int n_in,
                              void* d_out, int out_size, void* d_ws, size_t ws_size,
                              hipStream_t stream)
{
  const float* x   = (const float*)d_in[0];
  const float* h0  = (const float*)d_in[1];
  const float* c0  = (const float*)d_in[2];
  const float* rv0 = (const float*)d_in[3];
  const float* w0p = (const float*)d_in[4];
  const float* w1p = (const float*)d_in[5];
  const float* M   = (const float*)d_in[6];
  const float* W_k = (const float*)d_in[7];
  const float* W_r = (const float*)d_in[8];
  const float* b_l = (const float*)d_in[9];
  const float* W_p = (const float*)d_in[10];
  const float* b_p = (const float*)d_in[11];
  const float* W_o = (const float*)d_in[12];
  const float* b_o = (const float*)d_in[13];
  float* out = (float*)d_out;
  char* ws = (char*)d_ws;
  u16*   Wt    = (u16*)(ws + WS_WT);
  float* knb   = (float*)(ws + WS_P);
  float* oh_ws = (float*)(ws + WS_OH);

  k_transpose<<<dim3(16, 6), 256, 0, stream>>>(W_k, W_r, Wt);
  k_lstm<<<dim3(64, 8), 256, 0, stream>>>(x, rv0, h0, c0, b_l, Wt, out);
  k_params<<<512, 384, 0, stream>>>(out + OFF_H, W_p, b_p, W_o, knb, oh_ws);
  k_addr<<<4096, 256, 0, stream>>>(M, w0p, w1p, knb, oh_ws, W_o, b_o, out);
}